// Round 5
// baseline (719.982 us; speedup 1.0000x reference)
//
#include <hip/hip_runtime.h>
#include <hip/hip_bf16.h>

// Talking-head attention. B=2,N=2048,C=1024,H=16,D=64.
// Round 5: fused attention restructured for latency:
//  - 4-wave (256-thr) blocks, 2 blocks/CU (two independent barrier domains)
//  - mix1->mix2 redistribution via 4 ds_bpermute (__shfl) per point-group:
//    no E-overlay LDS round trip, no lgkmcnt(0) fence
//  - double-buffered S and F, ONE __syncthreads per 32-m step (both sweeps)
// All MFMA layouts / S packing / F swizzle carried bit-identical from the
// R4-passing kernel (word stride 324->260, same mod-32 residue, mod-4 aligned).

typedef __bf16 bf16_t;
typedef __bf16 bf16x8 __attribute__((ext_vector_type(8)));
typedef float f32x4 __attribute__((ext_vector_type(4)));

#define DEV static __device__ __forceinline__

static constexpr float NEGV = -1e9f;

DEV f32x4 mfma16(bf16x8 a, bf16x8 b, f32x4 c) {
  return __builtin_amdgcn_mfma_f32_16x16x32_bf16(a, b, c, 0, 0, 0);
}

DEV bf16x8 zero8() {
  bf16x8 z;
#pragma unroll
  for (int j = 0; j < 8; ++j) z[j] = (bf16_t)0.0f;
  return z;
}

DEV uint32_t pkbf(float lo, float hi) {
  union { bf16_t f; unsigned short s; } a, b;
  a.f = (bf16_t)lo; b.f = (bf16_t)hi;
  return (uint32_t)a.s | ((uint32_t)b.s << 16);
}

union U84 { uint32_t u[4]; bf16x8 v; };

// ---------------------------------------------------------------- mask prep
__global__ __launch_bounds__(256) void mask_prep(const unsigned char* __restrict__ raw,
                                                 unsigned char* __restrict__ canon,
                                                 unsigned char* __restrict__ allflag) {
  __shared__ int c0, c12, f0, f1;
  const int tid = threadIdx.x;
  if (tid == 0) { c0 = 0; c12 = 0; f0 = 1; f1 = 1; }
  __syncthreads();
  int l0 = 0, l12 = 0;
  for (int i = tid; i < 4096; i += 256) {
    unsigned char v = raw[i];
    if (v) {
      int r = i & 3;
      if (r == 0) l0++;
      else if (r < 3) l12++;
    }
  }
  if (l0) atomicAdd(&c0, l0);
  if (l12) atomicAdd(&c12, l12);
  __syncthreads();
  const int mode = (c0 == 0) ? 2 : ((c12 > 0) ? 0 : 1);
  for (int i = tid; i < 4096; i += 256) {
    bool t;
    if (mode == 0)      t = raw[i] != 0;
    else if (mode == 1) t = ((const int*)raw)[i] != 0;
    else                t = ((const float*)raw)[i] != 0.0f;
    canon[i] = t ? 1 : 0;
    if (!t) atomicAnd(i < 2048 ? &f0 : &f1, 0);
  }
  __syncthreads();
  if (tid == 0) { allflag[0] = (unsigned char)f0; allflag[1] = (unsigned char)f1; }
}

// ---------------------------------------------------------------- GEMM (unchanged)
__global__ __launch_bounds__(256) void gemm_kernel(
    const float* __restrict__ Af, const bf16_t* __restrict__ Ab,
    const float* __restrict__ Bw, const float* __restrict__ bias,
    float* __restrict__ outf,
    bf16_t* __restrict__ Qs, bf16_t* __restrict__ Ks, bf16_t* __restrict__ Vt,
    int K, int Nn, int epi) {
  __shared__ bf16_t As[64][40];
  __shared__ bf16_t Bs[64][40];
  const int tid = threadIdx.x;
  const int lane = tid & 63, wid = tid >> 6;
  const int bx = blockIdx.x, by = blockIdx.y;
  const int wr = (wid >> 1) * 32, wc = (wid & 1) * 32;
  const int lr = lane & 15, kq = lane >> 4;

  f32x4 acc[2][2];
#pragma unroll
  for (int i = 0; i < 2; ++i)
#pragma unroll
    for (int j = 0; j < 2; ++j) acc[i][j] = (f32x4){0.f, 0.f, 0.f, 0.f};

  for (int kt = 0; kt < K; kt += 32) {
    {
      const int row = tid >> 2, c8 = (tid & 3) * 8;
      if (epi == 0) {
        const float* p = Af + (size_t)(bx * 64 + row) * K + kt + c8;
        float4 v0 = *(const float4*)p;
        float4 v1 = *(const float4*)(p + 4);
        bf16x8 v;
        v[0] = (bf16_t)v0.x; v[1] = (bf16_t)v0.y; v[2] = (bf16_t)v0.z; v[3] = (bf16_t)v0.w;
        v[4] = (bf16_t)v1.x; v[5] = (bf16_t)v1.y; v[6] = (bf16_t)v1.z; v[7] = (bf16_t)v1.w;
        *(bf16x8*)&As[row][c8] = v;
      } else {
        *(bf16x8*)&As[row][c8] =
            *(const bf16x8*)(Ab + (size_t)(bx * 64 + row) * K + kt + c8);
      }
      const int krow = tid >> 3, n8 = (tid & 7) * 8;
      const float* bp = Bw + (size_t)(kt + krow) * Nn + by * 64 + n8;
      float4 b0 = *(const float4*)bp;
      float4 b1 = *(const float4*)(bp + 4);
      Bs[n8 + 0][krow] = (bf16_t)b0.x; Bs[n8 + 1][krow] = (bf16_t)b0.y;
      Bs[n8 + 2][krow] = (bf16_t)b0.z; Bs[n8 + 3][krow] = (bf16_t)b0.w;
      Bs[n8 + 4][krow] = (bf16_t)b1.x; Bs[n8 + 5][krow] = (bf16_t)b1.y;
      Bs[n8 + 6][krow] = (bf16_t)b1.z; Bs[n8 + 7][krow] = (bf16_t)b1.w;
    }
    __syncthreads();
#pragma unroll
    for (int rt = 0; rt < 2; ++rt) {
      bf16x8 af = *(const bf16x8*)&As[wr + rt * 16 + lr][kq * 8];
#pragma unroll
      for (int ct = 0; ct < 2; ++ct) {
        bf16x8 bf = *(const bf16x8*)&Bs[wc + ct * 16 + lr][kq * 8];
        acc[rt][ct] = mfma16(af, bf, acc[rt][ct]);
      }
    }
    __syncthreads();
  }

#pragma unroll
  for (int rt = 0; rt < 2; ++rt)
#pragma unroll
    for (int ct = 0; ct < 2; ++ct)
#pragma unroll
      for (int r = 0; r < 4; ++r) {
        const int grow = bx * 64 + wr + rt * 16 + kq * 4 + r;
        const int gcol = by * 64 + wc + ct * 16 + lr;
        const float v = acc[rt][ct][r] + bias[gcol];
        if (epi == 0) {
          const int t = gcol >> 10, h = (gcol >> 6) & 15, d = gcol & 63;
          const int b = grow >> 11, n = grow & 2047;
          if (t == 0)
            Qs[(((size_t)b * 16 + h) * 2048 + n) * 64 + d] = (bf16_t)(v * 0.125f);
          else if (t == 1)
            Ks[(((size_t)b * 16 + h) * 2048 + n) * 64 + d] = (bf16_t)v;
          else
            Vt[(((size_t)b * 16 + h) * 64 + d) * 2048 + n] = (bf16_t)v;
        } else {
          outf[(size_t)grow * Nn + gcol] = v;
        }
      }
}

// ---------------------------------------------------------------- V col-sum
__global__ __launch_bounds__(256) void vsum_kernel(const bf16_t* __restrict__ Vt,
                                                   float* __restrict__ Vsum) {
  const int lane = threadIdx.x & 63, wid = threadIdx.x >> 6;
  const int row = blockIdx.x * 4 + wid;
  const bf16_t* p = Vt + (size_t)row * 2048;
  float s = 0.f;
#pragma unroll
  for (int it = 0; it < 4; ++it) {
    bf16x8 v = *(const bf16x8*)(p + it * 512 + lane * 8);
#pragma unroll
    for (int j = 0; j < 8; ++j) s += (float)v[j];
  }
#pragma unroll
  for (int off = 32; off; off >>= 1) s += __shfl_xor(s, off);
  if (lane == 0) Vsum[row] = s;
}

// ---------------------------------------------------------------- fused attention
// 256 thr / 4 waves, n-tile 16, full m per block, grid 256 -> 2 blocks/CU.
// Wave w: QK + PV for heads {4w..4w+3}; mix for point-groups pg = 8w..8w+7.
// One __syncthreads per 32-m step. S,F double-buffered. mix1->mix2 via shfl.
__global__ __launch_bounds__(256, 2) void attn_fused(
    const bf16_t* __restrict__ Qs, const bf16_t* __restrict__ Ks,
    const bf16_t* __restrict__ Vt, const unsigned char* __restrict__ canon,
    const unsigned char* __restrict__ allflag,
    const float* __restrict__ Wl, const float* __restrict__ bl,
    const float* __restrict__ Ww, const float* __restrict__ bw,
    const float* __restrict__ Vsum, bf16_t* __restrict__ AO) {
  __shared__ uint32_t Sb[2][5120];      // 2 x 20480 B: packed S head-pair words
  __shared__ uint32_t Fb[2][16 * 260];  // 2 x 16640 B: F[g2][n16][16w swizzled +4 pad]
  const int tid = threadIdx.x, lane = tid & 63, wid = tid >> 6;
  const int c = lane & 15, kq = lane >> 4;
  const int id = blockIdx.x;
  const int b = id & 1;
  const int n0 = (id >> 1) * 16;
  const int h0 = 4 * wid;
  const bool allt = allflag[b] != 0;

  // dense talking-heads fragments (heads 0..15 at k-slots 0..15; kq>=2 zero)
  bf16x8 wlf, wwf;
#pragma unroll
  for (int j = 0; j < 8; ++j) {
    const int k = kq * 8 + j;
    wlf[j] = (k < 16) ? (bf16_t)Wl[k * 16 + c] : (bf16_t)0.0f;
    wwf[j] = (k < 16) ? (bf16_t)Ww[k * 16 + c] : (bf16_t)0.0f;
  }
  f32x4 blv;
#pragma unroll
  for (int r = 0; r < 4; ++r) blv[r] = bl[kq * 4 + r];

  // Q fragments rows n0..n0+15, 4 heads
  bf16x8 qf[4][2];
#pragma unroll
  for (int hh = 0; hh < 4; ++hh)
#pragma unroll
    for (int ks = 0; ks < 2; ++ks)
      qf[hh][ks] = *(const bf16x8*)(Qs + ((size_t)(b * 16 + h0 + hh) * 2048 + n0 + c) *
                                             64 + ks * 32 + kq * 8);

  // QK^T for m-step v -> packed S words (R4-proven layout, words 2wid,2wid+1)
  auto stage = [&](int v, uint32_t* sb) {
#pragma unroll
    for (int hp = 0; hp < 2; ++hp) {
      bf16x8 kf[2][2][2];
#pragma unroll
      for (int h2 = 0; h2 < 2; ++h2)
#pragma unroll
        for (int mt = 0; mt < 2; ++mt)
#pragma unroll
          for (int ks = 0; ks < 2; ++ks)
            kf[h2][mt][ks] =
                *(const bf16x8*)(Ks + ((size_t)(b * 16 + h0 + hp * 2 + h2) * 2048 +
                                       v * 32 + mt * 16 + c) * 64 + ks * 32 + kq * 8);
#pragma unroll
      for (int mt = 0; mt < 2; ++mt) {
        f32x4 a0 = (f32x4){0.f, 0.f, 0.f, 0.f};
        f32x4 a1 = (f32x4){0.f, 0.f, 0.f, 0.f};
        a0 = mfma16(qf[hp * 2 + 0][0], kf[0][mt][0], a0);
        a0 = mfma16(qf[hp * 2 + 0][1], kf[0][mt][1], a0);
        a1 = mfma16(qf[hp * 2 + 1][0], kf[1][mt][0], a1);
        a1 = mfma16(qf[hp * 2 + 1][1], kf[1][mt][1], a1);
#pragma unroll
        for (int r = 0; r < 4; ++r) {
          const int p = (kq * 4 + r) * 32 + mt * 16 + c;
          sb[p * 10 + ((2 * wid + hp) ^ (kq & 1))] = pkbf(a0[r], a1[r]);
        }
      }
    }
  };

  // dense S gather for point-row prow = (wid*8+pp)*16 + c (R4-proven decode)
  auto gatherS = [&](const uint32_t* sb, int pp) {
    const int prow = (wid * 8 + pp) * 16 + c;
    const int bp = (prow >> 7) & 1;
    if (kq < 2) {
      U84 t;
#pragma unroll
      for (int i = 0; i < 4; ++i) t.u[i] = sb[prow * 10 + ((kq * 4 + i) ^ bp)];
      return t.v;
    }
    return zero8();
  };

  // ---------------- sweep 1: row sums l (registers)
  float lacc[4][4];
#pragma unroll
  for (int r = 0; r < 4; ++r)
#pragma unroll
    for (int ns = 0; ns < 4; ++ns) lacc[r][ns] = 0.f;
  stage(0, Sb[0]);
  __syncthreads();
  for (int u = 0; u < 64; ++u) {
    const uint32_t* scur = Sb[u & 1];
    uint32_t* snxt = Sb[(u + 1) & 1];
#pragma unroll
    for (int pp = 0; pp < 8; ++pp) {
      bf16x8 sf = gatherS(scur, pp);
      f32x4 d1 = mfma16(wlf, sf, blv);  // D[g=4kq+r][point (wid*8+pp)*16+c]
      if (!allt && !canon[b * 2048 + u * 32 + (pp & 1) * 16 + c]) {
        d1[0] += NEGV; d1[1] += NEGV; d1[2] += NEGV; d1[3] += NEGV;
      }
      const int ns = pp >> 1;
#pragma unroll
      for (int r = 0; r < 4; ++r) lacc[r][ns] += __expf(d1[r]);
    }
    if (u < 63) stage(u + 1, snxt);
    __syncthreads();
  }
  float invl[4][4];
#pragma unroll
  for (int r = 0; r < 4; ++r)
#pragma unroll
    for (int ns = 0; ns < 4; ++ns) {
      float s = lacc[r][ns];
      s += __shfl_xor(s, 1);
      s += __shfl_xor(s, 2);
      s += __shfl_xor(s, 4);
      s += __shfl_xor(s, 8);
      invl[r][ns] = 1.0f / s;
    }

  // ---------------- sweep 2: normalize, mix2 via shfl, PV (1 bar/u)
  f32x4 oacc[4][4];
#pragma unroll
  for (int i = 0; i < 4; ++i)
#pragma unroll
    for (int j = 0; j < 4; ++j) oacc[i][j] = (f32x4){0.f, 0.f, 0.f, 0.f};
  stage(0, Sb[0]);
  __syncthreads();
  for (int u = 0; u < 64; ++u) {
    const uint32_t* scur = Sb[u & 1];
    uint32_t* snxt = Sb[(u + 1) & 1];
    bf16_t* fcur = (bf16_t*)Fb[u & 1];
    const uint32_t* fprev = Fb[(u + 1) & 1];  // F(u-1) when u>0
    if (u > 0) {
      // PV(u-1): b128 F reads + V global, 16 MFMA
#pragma unroll
      for (int hh = 0; hh < 4; ++hh) {
        const int g2 = h0 + hh;
        bf16x8 af = *(const bf16x8*)&fprev[g2 * 260 + c * 16 + ((kq ^ (c & 3)) << 2)];
#pragma unroll
        for (int dt = 0; dt < 4; ++dt) {
          bf16x8 vf = *(const bf16x8*)(Vt + ((size_t)(b * 16 + g2) * 64 + dt * 16 + c) *
                                                2048 + (u - 1) * 32 + kq * 8);
          oacc[hh][dt] = mfma16(af, vf, oacc[hh][dt]);
        }
      }
    }
    // mix(u): mix1 -> exp*invl -> shfl redistribute -> mix2 -> F stage
#pragma unroll
    for (int pp = 0; pp < 8; ++pp) {
      bf16x8 sf = gatherS(scur, pp);
      f32x4 d1 = mfma16(wlf, sf, blv);
      if (!allt && !canon[b * 2048 + u * 32 + (pp & 1) * 16 + c]) {
        d1[0] += NEGV; d1[1] += NEGV; d1[2] += NEGV; d1[3] += NEGV;
      }
      const int ns = pp >> 1;
      const float e0 = __expf(d1[0]) * invl[0][ns];
      const float e1 = __expf(d1[1]) * invl[1][ns];
      const float e2 = __expf(d1[2]) * invl[2][ns];
      const float e3 = __expf(d1[3]) * invl[3][ns];
      const uint32_t Aw = pkbf(e0, e1);  // g = 4kq, 4kq+1
      const uint32_t Bw2 = pkbf(e2, e3); // g = 4kq+2, 4kq+3
      // redistribute: dest lane (c,kq') slot-pair i needs words from lane
      // c + 16*(2kq' + (i>>1)) (i even: A, i odd: B)
      const int s0 = (c + 32 * kq) & 63;
      const int s1 = (s0 + 16) & 63;
      U84 ef;
      ef.u[0] = (uint32_t)__shfl((int)Aw, s0);
      ef.u[1] = (uint32_t)__shfl((int)Bw2, s0);
      ef.u[2] = (uint32_t)__shfl((int)Aw, s1);
      ef.u[3] = (uint32_t)__shfl((int)Bw2, s1);
      bf16x8 efv = (kq < 2) ? ef.v : zero8();
      f32x4 d2 = mfma16(wwf, efv, (f32x4){0.f, 0.f, 0.f, 0.f});  // F[g2=4kq+r][prow]
      const int pg = wid * 8 + pp;
      const int nl = pg >> 1, ml = (pg & 1) * 16 + c;
      const int wm = (ml >> 1) ^ ((nl & 3) << 2);
#pragma unroll
      for (int r = 0; r < 4; ++r)
        fcur[(kq * 4 + r) * 520 + nl * 32 + wm * 2 + (ml & 1)] = (bf16_t)d2[r];
    }
    if (u < 63) stage(u + 1, snxt);
    __syncthreads();
  }
  // PV(63) epilogue from Fb[1]
  {
    const uint32_t* fprev = Fb[1];
#pragma unroll
    for (int hh = 0; hh < 4; ++hh) {
      const int g2 = h0 + hh;
      bf16x8 af = *(const bf16x8*)&fprev[g2 * 260 + c * 16 + ((kq ^ (c & 3)) << 2)];
#pragma unroll
      for (int dt = 0; dt < 4; ++dt) {
        bf16x8 vf = *(const bf16x8*)(Vt + ((size_t)(b * 16 + g2) * 64 + dt * 16 + c) *
                                              2048 + 63 * 32 + kq * 8);
        oacc[hh][dt] = mfma16(af, vf, oacc[hh][dt]);
      }
    }
  }

  // ---------------- epilogue: O + bw * Vsum -> AO (bf16)
#pragma unroll
  for (int hh = 0; hh < 4; ++hh) {
    const int g2 = h0 + hh;
    const float bwv = bw[g2];
#pragma unroll
    for (int dt = 0; dt < 4; ++dt) {
      const float vs = Vsum[(size_t)(b * 16 + g2) * 64 + dt * 16 + c];
#pragma unroll
      for (int r = 0; r < 4; ++r) {
        const int n = n0 + kq * 4 + r;
        AO[((size_t)b * 2048 + n) * 1024 + g2 * 64 + dt * 16 + c] =
            (bf16_t)(oacc[hh][dt][r] + bwv * vs);
      }
    }
  }
}

// ---------------------------------------------------------------- launch
extern "C" void kernel_launch(void* const* d_in, const int* in_sizes, int n_in,
                              void* d_out, int out_size, void* d_ws, size_t ws_size,
                              hipStream_t stream) {
  const float* x = (const float*)d_in[0];
  const unsigned char* mask = (const unsigned char*)d_in[1];
  const float* Wqkv = (const float*)d_in[2];
  const float* bqkv = (const float*)d_in[3];
  const float* Wl = (const float*)d_in[4];
  const float* bl = (const float*)d_in[5];
  const float* Ww = (const float*)d_in[6];
  const float* bw = (const float*)d_in[7];
  const float* Wp = (const float*)d_in[8];
  const float* bp = (const float*)d_in[9];
  float* out = (float*)d_out;

  char* w = (char*)d_ws;
  auto alloc = [&](size_t bytes) {
    char* p = w;
    w += (bytes + 255) & ~(size_t)255;
    return p;
  };
  bf16_t* Qs = (bf16_t*)alloc((size_t)2 * 16 * 2048 * 64 * 2);
  bf16_t* Ks = (bf16_t*)alloc((size_t)2 * 16 * 2048 * 64 * 2);
  bf16_t* Vt = (bf16_t*)alloc((size_t)2 * 16 * 2048 * 64 * 2);
  bf16_t* AO = (bf16_t*)alloc((size_t)4096 * 1024 * 2);
  float* Vsum = (float*)alloc((size_t)2048 * 4);
  unsigned char* canon = (unsigned char*)alloc(4096);
  unsigned char* allflag = (unsigned char*)alloc(256);

  mask_prep<<<dim3(1), dim3(256), 0, stream>>>(mask, canon, allflag);
  gemm_kernel<<<dim3(64, 48), dim3(256), 0, stream>>>(
      x, (const bf16_t*)nullptr, Wqkv, bqkv, nullptr, Qs, Ks, Vt, 1024, 3072, 0);
  vsum_kernel<<<dim3(512), dim3(256), 0, stream>>>(Vt, Vsum);
  attn_fused<<<dim3(256), dim3(256), 0, stream>>>(Qs, Ks, Vt, canon, allflag, Wl, bl,
                                                  Ww, bw, Vsum, AO);
  gemm_kernel<<<dim3(64, 16), dim3(256), 0, stream>>>(
      (const float*)nullptr, AO, Wp, bp, out, nullptr, nullptr, nullptr, 1024, 1024, 1);
}

// Round 8
// 581.798 us; speedup vs baseline: 1.2375x; 1.2375x over previous
//
#include <hip/hip_runtime.h>
#include <hip/hip_bf16.h>

// Talking-head attention. B=2,N=2048,C=1024,H=16,D=64.
// Round 8: empirical bisection. R6's split scaffolding (pass1 stats -> merge ->
// pass2 -> reduce) kept, but BOTH attention passes are verbatim clones of the
// R5-PASSING 4-wave sweeps: same stage (stride-10 S, word (2wid+hp)^(kq&1)),
// same gatherS, same shfl mix1->mix2, same 520-stride F layout, same PV, same
// launch_bounds(256,2). Only deltas vs R5: mbeg m-chunk offset, fin/pstats IO,
// Opart partial write. Isolates the R6/R3 failure to either the 8-wave remap
// (if this passes) or the split scaffolding (if this fails).

typedef __bf16 bf16_t;
typedef __bf16 bf16x8 __attribute__((ext_vector_type(8)));
typedef float f32x4 __attribute__((ext_vector_type(4)));

#define DEV static __device__ __forceinline__

static constexpr float NEGV = -1e9f;

DEV f32x4 mfma16(bf16x8 a, bf16x8 b, f32x4 c) {
  return __builtin_amdgcn_mfma_f32_16x16x32_bf16(a, b, c, 0, 0, 0);
}

DEV bf16x8 zero8() {
  bf16x8 z;
#pragma unroll
  for (int j = 0; j < 8; ++j) z[j] = (bf16_t)0.0f;
  return z;
}

DEV uint32_t pkbf(float lo, float hi) {
  union { bf16_t f; unsigned short s; } a, b;
  a.f = (bf16_t)lo; b.f = (bf16_t)hi;
  return (uint32_t)a.s | ((uint32_t)b.s << 16);
}

union U84 { uint32_t u[4]; bf16x8 v; };

// ---------------------------------------------------------------- mask prep
__global__ __launch_bounds__(256) void mask_prep(const unsigned char* __restrict__ raw,
                                                 unsigned char* __restrict__ canon,
                                                 unsigned char* __restrict__ allflag) {
  __shared__ int c0, c12, f0, f1;
  const int tid = threadIdx.x;
  if (tid == 0) { c0 = 0; c12 = 0; f0 = 1; f1 = 1; }
  __syncthreads();
  int l0 = 0, l12 = 0;
  for (int i = tid; i < 4096; i += 256) {
    unsigned char v = raw[i];
    if (v) {
      int r = i & 3;
      if (r == 0) l0++;
      else if (r < 3) l12++;
    }
  }
  if (l0) atomicAdd(&c0, l0);
  if (l12) atomicAdd(&c12, l12);
  __syncthreads();
  const int mode = (c0 == 0) ? 2 : ((c12 > 0) ? 0 : 1);
  for (int i = tid; i < 4096; i += 256) {
    bool t;
    if (mode == 0)      t = raw[i] != 0;
    else if (mode == 1) t = ((const int*)raw)[i] != 0;
    else                t = ((const float*)raw)[i] != 0.0f;
    canon[i] = t ? 1 : 0;
    if (!t) atomicAnd(i < 2048 ? &f0 : &f1, 0);
  }
  __syncthreads();
  if (tid == 0) { allflag[0] = (unsigned char)f0; allflag[1] = (unsigned char)f1; }
}

// ---------------------------------------------------------------- GEMM (unchanged)
__global__ __launch_bounds__(256) void gemm_kernel(
    const float* __restrict__ Af, const bf16_t* __restrict__ Ab,
    const float* __restrict__ Bw, const float* __restrict__ bias,
    float* __restrict__ outf,
    bf16_t* __restrict__ Qs, bf16_t* __restrict__ Ks, bf16_t* __restrict__ Vt,
    int K, int Nn, int epi) {
  __shared__ bf16_t As[64][40];
  __shared__ bf16_t Bs[64][40];
  const int tid = threadIdx.x;
  const int lane = tid & 63, wid = tid >> 6;
  const int bx = blockIdx.x, by = blockIdx.y;
  const int wr = (wid >> 1) * 32, wc = (wid & 1) * 32;
  const int lr = lane & 15, kq = lane >> 4;

  f32x4 acc[2][2];
#pragma unroll
  for (int i = 0; i < 2; ++i)
#pragma unroll
    for (int j = 0; j < 2; ++j) acc[i][j] = (f32x4){0.f, 0.f, 0.f, 0.f};

  for (int kt = 0; kt < K; kt += 32) {
    {
      const int row = tid >> 2, c8 = (tid & 3) * 8;
      if (epi == 0) {
        const float* p = Af + (size_t)(bx * 64 + row) * K + kt + c8;
        float4 v0 = *(const float4*)p;
        float4 v1 = *(const float4*)(p + 4);
        bf16x8 v;
        v[0] = (bf16_t)v0.x; v[1] = (bf16_t)v0.y; v[2] = (bf16_t)v0.z; v[3] = (bf16_t)v0.w;
        v[4] = (bf16_t)v1.x; v[5] = (bf16_t)v1.y; v[6] = (bf16_t)v1.z; v[7] = (bf16_t)v1.w;
        *(bf16x8*)&As[row][c8] = v;
      } else {
        *(bf16x8*)&As[row][c8] =
            *(const bf16x8*)(Ab + (size_t)(bx * 64 + row) * K + kt + c8);
      }
      const int krow = tid >> 3, n8 = (tid & 7) * 8;
      const float* bp = Bw + (size_t)(kt + krow) * Nn + by * 64 + n8;
      float4 b0 = *(const float4*)bp;
      float4 b1 = *(const float4*)(bp + 4);
      Bs[n8 + 0][krow] = (bf16_t)b0.x; Bs[n8 + 1][krow] = (bf16_t)b0.y;
      Bs[n8 + 2][krow] = (bf16_t)b0.z; Bs[n8 + 3][krow] = (bf16_t)b0.w;
      Bs[n8 + 4][krow] = (bf16_t)b1.x; Bs[n8 + 5][krow] = (bf16_t)b1.y;
      Bs[n8 + 6][krow] = (bf16_t)b1.z; Bs[n8 + 7][krow] = (bf16_t)b1.w;
    }
    __syncthreads();
#pragma unroll
    for (int rt = 0; rt < 2; ++rt) {
      bf16x8 af = *(const bf16x8*)&As[wr + rt * 16 + lr][kq * 8];
#pragma unroll
      for (int ct = 0; ct < 2; ++ct) {
        bf16x8 bf = *(const bf16x8*)&Bs[wc + ct * 16 + lr][kq * 8];
        acc[rt][ct] = mfma16(af, bf, acc[rt][ct]);
      }
    }
    __syncthreads();
  }

#pragma unroll
  for (int rt = 0; rt < 2; ++rt)
#pragma unroll
    for (int ct = 0; ct < 2; ++ct)
#pragma unroll
      for (int r = 0; r < 4; ++r) {
        const int grow = bx * 64 + wr + rt * 16 + kq * 4 + r;
        const int gcol = by * 64 + wc + ct * 16 + lr;
        const float v = acc[rt][ct][r] + bias[gcol];
        if (epi == 0) {
          const int t = gcol >> 10, h = (gcol >> 6) & 15, d = gcol & 63;
          const int b = grow >> 11, n = grow & 2047;
          if (t == 0)
            Qs[(((size_t)b * 16 + h) * 2048 + n) * 64 + d] = (bf16_t)(v * 0.125f);
          else if (t == 1)
            Ks[(((size_t)b * 16 + h) * 2048 + n) * 64 + d] = (bf16_t)v;
          else
            Vt[(((size_t)b * 16 + h) * 64 + d) * 2048 + n] = (bf16_t)v;
        } else {
          outf[(size_t)grow * Nn + gcol] = v;
        }
      }
}

// ---------------------------------------------------------------- V col-sum
__global__ __launch_bounds__(256) void vsum_kernel(const bf16_t* __restrict__ Vt,
                                                   float* __restrict__ Vsum) {
  const int lane = threadIdx.x & 63, wid = threadIdx.x >> 6;
  const int row = blockIdx.x * 4 + wid;
  const bf16_t* p = Vt + (size_t)row * 2048;
  float s = 0.f;
#pragma unroll
  for (int it = 0; it < 4; ++it) {
    bf16x8 v = *(const bf16x8*)(p + it * 512 + lane * 8);
#pragma unroll
    for (int j = 0; j < 8; ++j) s += (float)v[j];
  }
#pragma unroll
  for (int off = 32; off; off >>= 1) s += __shfl_xor(s, off);
  if (lane == 0) Vsum[row] = s;
}

// ---------------------------------------------------------------- pass 1 (stats)
// Verbatim R5 sweep-1 geometry: 256 thr / 4 waves, n-tile 16, wave w = heads
// 4w..4w+3, pg = wid*8+pp, stride-10 S, dbuf, 1 barrier/u. m-chunk 512 (16 u).
// Grid 1024. Output: partial row-sums pstats[b*4+mc][n][g].
__global__ __launch_bounds__(256, 2) void attn_pass1(
    const bf16_t* __restrict__ Qs, const bf16_t* __restrict__ Ks,
    const unsigned char* __restrict__ canon, const unsigned char* __restrict__ allflag,
    const float* __restrict__ Wl, const float* __restrict__ bl,
    float* __restrict__ pstats) {
  __shared__ uint32_t Sb[2][5120];
  const int tid = threadIdx.x, lane = tid & 63, wid = tid >> 6;
  const int c = lane & 15, kq = lane >> 4;
  const int job = (blockIdx.x & 7) * 128 + (blockIdx.x >> 3);  // XCD-clustered
  const int mc = job >> 8, b = (job >> 7) & 1, nt = job & 127;
  const int n0 = nt * 16, mbeg = mc * 512;
  const int h0 = 4 * wid;
  const bool allt = allflag[b] != 0;

  bf16x8 wlf;
#pragma unroll
  for (int j = 0; j < 8; ++j) {
    const int k = kq * 8 + j;
    wlf[j] = (k < 16) ? (bf16_t)Wl[k * 16 + c] : (bf16_t)0.0f;
  }
  f32x4 blv;
#pragma unroll
  for (int r = 0; r < 4; ++r) blv[r] = bl[kq * 4 + r];

  bf16x8 qf[4][2];
#pragma unroll
  for (int hh = 0; hh < 4; ++hh)
#pragma unroll
    for (int ks = 0; ks < 2; ++ks)
      qf[hh][ks] = *(const bf16x8*)(Qs + ((size_t)(b * 16 + h0 + hh) * 2048 + n0 + c) *
                                             64 + ks * 32 + kq * 8);

  auto stage = [&](int v, uint32_t* sb) {
    const int m0 = mbeg + v * 32;
#pragma unroll
    for (int hp = 0; hp < 2; ++hp) {
      bf16x8 kf[2][2][2];
#pragma unroll
      for (int h2 = 0; h2 < 2; ++h2)
#pragma unroll
        for (int mt = 0; mt < 2; ++mt)
#pragma unroll
          for (int ks = 0; ks < 2; ++ks)
            kf[h2][mt][ks] =
                *(const bf16x8*)(Ks + ((size_t)(b * 16 + h0 + hp * 2 + h2) * 2048 +
                                       m0 + mt * 16 + c) * 64 + ks * 32 + kq * 8);
#pragma unroll
      for (int mt = 0; mt < 2; ++mt) {
        f32x4 a0 = (f32x4){0.f, 0.f, 0.f, 0.f};
        f32x4 a1 = (f32x4){0.f, 0.f, 0.f, 0.f};
        a0 = mfma16(qf[hp * 2 + 0][0], kf[0][mt][0], a0);
        a0 = mfma16(qf[hp * 2 + 0][1], kf[0][mt][1], a0);
        a1 = mfma16(qf[hp * 2 + 1][0], kf[1][mt][0], a1);
        a1 = mfma16(qf[hp * 2 + 1][1], kf[1][mt][1], a1);
#pragma unroll
        for (int r = 0; r < 4; ++r) {
          const int p = (kq * 4 + r) * 32 + mt * 16 + c;
          sb[p * 10 + ((2 * wid + hp) ^ (kq & 1))] = pkbf(a0[r], a1[r]);
        }
      }
    }
  };

  auto gatherS = [&](const uint32_t* sb, int pp) {
    const int prow = (wid * 8 + pp) * 16 + c;
    const int bp = (prow >> 7) & 1;
    if (kq < 2) {
      U84 t;
#pragma unroll
      for (int i = 0; i < 4; ++i) t.u[i] = sb[prow * 10 + ((kq * 4 + i) ^ bp)];
      return t.v;
    }
    return zero8();
  };

  float lacc[4][4];
#pragma unroll
  for (int r = 0; r < 4; ++r)
#pragma unroll
    for (int ns = 0; ns < 4; ++ns) lacc[r][ns] = 0.f;

  stage(0, Sb[0]);
  __syncthreads();
  for (int u = 0; u < 16; ++u) {
#pragma unroll
    for (int pp = 0; pp < 8; ++pp) {
      bf16x8 sf = gatherS(Sb[u & 1], pp);
      f32x4 d1 = mfma16(wlf, sf, blv);
      if (!allt && !canon[b * 2048 + mbeg + u * 32 + (pp & 1) * 16 + c]) {
        d1[0] += NEGV; d1[1] += NEGV; d1[2] += NEGV; d1[3] += NEGV;
      }
      const int ns = pp >> 1;
#pragma unroll
      for (int r = 0; r < 4; ++r) lacc[r][ns] += __expf(d1[r]);
    }
    if (u < 15) stage(u + 1, Sb[(u + 1) & 1]);
    __syncthreads();
  }

#pragma unroll
  for (int r = 0; r < 4; ++r)
#pragma unroll
    for (int ns = 0; ns < 4; ++ns) {
      float s = lacc[r][ns];
      s += __shfl_xor(s, 1);
      s += __shfl_xor(s, 2);
      s += __shfl_xor(s, 4);
      s += __shfl_xor(s, 8);
      if (c == 0)
        pstats[((size_t)(b * 4 + mc) * 2048 + n0 + wid * 4 + ns) * 16 + kq * 4 + r] = s;
    }
}

// ---------------------------------------------------------------- merge: 1/l
__global__ __launch_bounds__(256) void stats_merge(const float* __restrict__ ps,
                                                   float* __restrict__ fin) {
  const int i = blockIdx.x * 256 + threadIdx.x;  // over B*N*16 = 65536
  const int b = i >> 15, rest = i & 32767;
  float s = 0.f;
#pragma unroll
  for (int ch = 0; ch < 4; ++ch) s += ps[((size_t)(b * 4 + ch) << 15) + rest];
  fin[i] = 1.0f / s;
}

// ---------------------------------------------------------------- pass 2
// Verbatim R5 sweep-2: 256 thr / 4 waves, PV(u-1) -> mix(u) -> stage(u+1) ->
// barrier, dbuf S (stride 10) + F (520-stride), shfl mix1->mix2. m-chunk 1024
// (32 u). Grid 512 -> 2 independent 4-wave barrier domains per CU.
__global__ __launch_bounds__(256, 2) void attn_pass2(
    const bf16_t* __restrict__ Qs, const bf16_t* __restrict__ Ks,
    const bf16_t* __restrict__ Vt, const unsigned char* __restrict__ canon,
    const unsigned char* __restrict__ allflag,
    const float* __restrict__ Wl, const float* __restrict__ bl,
    const float* __restrict__ Ww, const float* __restrict__ fin,
    float* __restrict__ Opart) {
  __shared__ uint32_t Sb[2][5120];
  __shared__ uint32_t Fb[2][16 * 260];
  const int tid = threadIdx.x, lane = tid & 63, wid = tid >> 6;
  const int c = lane & 15, kq = lane >> 4;
  const int job = (blockIdx.x & 7) * 64 + (blockIdx.x >> 3);  // XCD-clustered
  const int mc = job >> 8, b = (job >> 7) & 1, nt = job & 127;
  const int n0 = nt * 16, mbeg = mc * 1024;
  const int h0 = 4 * wid;
  const bool allt = allflag[b] != 0;

  bf16x8 wlf, wwf;
#pragma unroll
  for (int j = 0; j < 8; ++j) {
    const int k = kq * 8 + j;
    wlf[j] = (k < 16) ? (bf16_t)Wl[k * 16 + c] : (bf16_t)0.0f;
    wwf[j] = (k < 16) ? (bf16_t)Ww[k * 16 + c] : (bf16_t)0.0f;
  }
  f32x4 blv;
#pragma unroll
  for (int r = 0; r < 4; ++r) blv[r] = bl[kq * 4 + r];

  float4 ivv[4];
#pragma unroll
  for (int ns = 0; ns < 4; ++ns)
    ivv[ns] =
        *(const float4*)&fin[((size_t)b * 2048 + n0 + wid * 4 + ns) * 16 + kq * 4];

  bf16x8 qf[4][2];
#pragma unroll
  for (int hh = 0; hh < 4; ++hh)
#pragma unroll
    for (int ks = 0; ks < 2; ++ks)
      qf[hh][ks] = *(const bf16x8*)(Qs + ((size_t)(b * 16 + h0 + hh) * 2048 + n0 + c) *
                                             64 + ks * 32 + kq * 8);

  auto stage = [&](int v, uint32_t* sb) {
    const int m0 = mbeg + v * 32;
#pragma unroll
    for (int hp = 0; hp < 2; ++hp) {
      bf16x8 kf[2][2][2];
#pragma unroll
      for (int h2 = 0; h2 < 2; ++h2)
#pragma unroll
        for (int mt = 0; mt < 2; ++mt)
#pragma unroll
          for (int ks = 0; ks < 2; ++ks)
            kf[h2][mt][ks] =
                *(const bf16x8*)(Ks + ((size_t)(b * 16 + h0 + hp * 2 + h2) * 2048 +
                                       m0 + mt * 16 + c) * 64 + ks * 32 + kq * 8);
#pragma unroll
      for (int mt = 0; mt < 2; ++mt) {
        f32x4 a0 = (f32x4){0.f, 0.f, 0.f, 0.f};
        f32x4 a1 = (f32x4){0.f, 0.f, 0.f, 0.f};
        a0 = mfma16(qf[hp * 2 + 0][0], kf[0][mt][0], a0);
        a0 = mfma16(qf[hp * 2 + 0][1], kf[0][mt][1], a0);
        a1 = mfma16(qf[hp * 2 + 1][0], kf[1][mt][0], a1);
        a1 = mfma16(qf[hp * 2 + 1][1], kf[1][mt][1], a1);
#pragma unroll
        for (int r = 0; r < 4; ++r) {
          const int p = (kq * 4 + r) * 32 + mt * 16 + c;
          sb[p * 10 + ((2 * wid + hp) ^ (kq & 1))] = pkbf(a0[r], a1[r]);
        }
      }
    }
  };

  auto gatherS = [&](const uint32_t* sb, int pp) {
    const int prow = (wid * 8 + pp) * 16 + c;
    const int bp = (prow >> 7) & 1;
    if (kq < 2) {
      U84 t;
#pragma unroll
      for (int i = 0; i < 4; ++i) t.u[i] = sb[prow * 10 + ((kq * 4 + i) ^ bp)];
      return t.v;
    }
    return zero8();
  };

  f32x4 oacc[4][4];
#pragma unroll
  for (int i = 0; i < 4; ++i)
#pragma unroll
    for (int j = 0; j < 4; ++j) oacc[i][j] = (f32x4){0.f, 0.f, 0.f, 0.f};

  stage(0, Sb[0]);
  __syncthreads();
  for (int u = 0; u < 32; ++u) {
    const uint32_t* scur = Sb[u & 1];
    uint32_t* snxt = Sb[(u + 1) & 1];
    bf16_t* fcur = (bf16_t*)Fb[u & 1];
    const uint32_t* fprev = Fb[(u + 1) & 1];  // F(u-1) when u>0
    if (u > 0) {
#pragma unroll
      for (int hh = 0; hh < 4; ++hh) {
        const int g2 = h0 + hh;
        bf16x8 af = *(const bf16x8*)&fprev[g2 * 260 + c * 16 + ((kq ^ (c & 3)) << 2)];
#pragma unroll
        for (int dt = 0; dt < 4; ++dt) {
          bf16x8 vf = *(const bf16x8*)(Vt + ((size_t)(b * 16 + g2) * 64 + dt * 16 + c) *
                                                2048 + mbeg + (u - 1) * 32 + kq * 8);
          oacc[hh][dt] = mfma16(af, vf, oacc[hh][dt]);
        }
      }
    }
#pragma unroll
    for (int pp = 0; pp < 8; ++pp) {
      bf16x8 sf = gatherS(scur, pp);
      f32x4 d1 = mfma16(wlf, sf, blv);
      if (!allt && !canon[b * 2048 + mbeg + u * 32 + (pp & 1) * 16 + c]) {
        d1[0] += NEGV; d1[1] += NEGV; d1[2] += NEGV; d1[3] += NEGV;
      }
      const int ns = pp >> 1;
      const float e0 = __expf(d1[0]) * ivv[ns].x;
      const float e1 = __expf(d1[1]) * ivv[ns].y;
      const float e2 = __expf(d1[2]) * ivv[ns].z;
      const float e3 = __expf(d1[3]) * ivv[ns].w;
      const uint32_t Aw = pkbf(e0, e1);
      const uint32_t Bw2 = pkbf(e2, e3);
      const int s0 = (c + 32 * kq) & 63;
      const int s1 = (s0 + 16) & 63;
      U84 ef;
      ef.u[0] = (uint32_t)__shfl((int)Aw, s0);
      ef.u[1] = (uint32_t)__shfl((int)Bw2, s0);
      ef.u[2] = (uint32_t)__shfl((int)Aw, s1);
      ef.u[3] = (uint32_t)__shfl((int)Bw2, s1);
      bf16x8 efv = (kq < 2) ? ef.v : zero8();
      f32x4 d2 = mfma16(wwf, efv, (f32x4){0.f, 0.f, 0.f, 0.f});  // F[g2=4kq+r][prow]
      const int pg = wid * 8 + pp;
      const int nl = pg >> 1, ml = (pg & 1) * 16 + c;
      const int wm = (ml >> 1) ^ ((nl & 3) << 2);
#pragma unroll
      for (int r = 0; r < 4; ++r)
        fcur[(kq * 4 + r) * 520 + nl * 32 + wm * 2 + (ml & 1)] = (bf16_t)d2[r];
    }
    if (u < 31) stage(u + 1, snxt);
    __syncthreads();
  }
  // epilogue PV(31) from Fb[1]
  {
    const uint32_t* fprev = Fb[1];
#pragma unroll
    for (int hh = 0; hh < 4; ++hh) {
      const int g2 = h0 + hh;
      bf16x8 af = *(const bf16x8*)&fprev[g2 * 260 + c * 16 + ((kq ^ (c & 3)) << 2)];
#pragma unroll
      for (int dt = 0; dt < 4; ++dt) {
        bf16x8 vf = *(const bf16x8*)(Vt + ((size_t)(b * 16 + g2) * 64 + dt * 16 + c) *
                                              2048 + mbeg + 31 * 32 + kq * 8);
        oacc[hh][dt] = mfma16(af, vf, oacc[hh][dt]);
      }
    }
  }

  // partial O write: [b][mc][n][col] f32
#pragma unroll
  for (int hh = 0; hh < 4; ++hh)
#pragma unroll
    for (int dt = 0; dt < 4; ++dt)
#pragma unroll
      for (int r = 0; r < 4; ++r) {
        const int n = n0 + kq * 4 + r;
        const int col = (h0 + hh) * 64 + dt * 16 + c;
        Opart[(((size_t)b * 2 + mc) * 2048 + n) * 1024 + col] = oacc[hh][dt][r];
      }
}

// ---------------------------------------------------------------- reduce (R2-proven)
__global__ __launch_bounds__(256) void reduce_ao(const float* __restrict__ Opart,
                                                 const float* __restrict__ bw,
                                                 const float* __restrict__ Vsum,
                                                 bf16_t* __restrict__ AO) {
  const size_t i = ((size_t)blockIdx.x * 256 + threadIdx.x) * 4;
  const int c = (int)(i & 1023), n = (int)((i >> 10) & 2047), b = (int)(i >> 21);
  const float4 p0 = *(const float4*)&Opart[(((size_t)b * 2 + 0) * 2048 + n) * 1024 + c];
  const float4 p1 = *(const float4*)&Opart[(((size_t)b * 2 + 1) * 2048 + n) * 1024 + c];
  float vv[4] = {p0.x + p1.x, p0.y + p1.y, p0.z + p1.z, p0.w + p1.w};
#pragma unroll
  for (int j = 0; j < 4; ++j) {
    const int cj = c + j, g2 = cj >> 6, d = cj & 63;
    AO[i + j] = (bf16_t)(vv[j] + bw[g2] * Vsum[((size_t)b * 16 + g2) * 64 + d]);
  }
}

// ---------------------------------------------------------------- launch
extern "C" void kernel_launch(void* const* d_in, const int* in_sizes, int n_in,
                              void* d_out, int out_size, void* d_ws, size_t ws_size,
                              hipStream_t stream) {
  const float* x = (const float*)d_in[0];
  const unsigned char* mask = (const unsigned char*)d_in[1];
  const float* Wqkv = (const float*)d_in[2];
  const float* bqkv = (const float*)d_in[3];
  const float* Wl = (const float*)d_in[4];
  const float* bl = (const float*)d_in[5];
  const float* Ww = (const float*)d_in[6];
  const float* bw = (const float*)d_in[7];
  const float* Wp = (const float*)d_in[8];
  const float* bp = (const float*)d_in[9];
  float* out = (float*)d_out;

  char* w = (char*)d_ws;
  auto alloc = [&](size_t bytes) {
    char* p = w;
    w += (bytes + 255) & ~(size_t)255;
    return p;
  };
  bf16_t* Qs = (bf16_t*)alloc((size_t)2 * 16 * 2048 * 64 * 2);
  bf16_t* Ks = (bf16_t*)alloc((size_t)2 * 16 * 2048 * 64 * 2);
  bf16_t* Vt = (bf16_t*)alloc((size_t)2 * 16 * 2048 * 64 * 2);
  bf16_t* AO = (bf16_t*)alloc((size_t)4096 * 1024 * 2);
  float* Opart = (float*)alloc((size_t)4 * 2048 * 1024 * 4);
  float* pstats = (float*)alloc((size_t)8 * 2048 * 16 * 4);
  float* fstats = (float*)alloc((size_t)2 * 2048 * 16 * 4);
  float* Vsum = (float*)alloc((size_t)2048 * 4);
  unsigned char* canon = (unsigned char*)alloc(4096);
  unsigned char* allflag = (unsigned char*)alloc(256);

  mask_prep<<<dim3(1), dim3(256), 0, stream>>>(mask, canon, allflag);
  gemm_kernel<<<dim3(64, 48), dim3(256), 0, stream>>>(
      x, (const bf16_t*)nullptr, Wqkv, bqkv, nullptr, Qs, Ks, Vt, 1024, 3072, 0);
  vsum_kernel<<<dim3(512), dim3(256), 0, stream>>>(Vt, Vsum);
  attn_pass1<<<dim3(1024), dim3(256), 0, stream>>>(Qs, Ks, canon, allflag, Wl, bl,
                                                   pstats);
  stats_merge<<<dim3(256), dim3(256), 0, stream>>>(pstats, fstats);
  attn_pass2<<<dim3(512), dim3(256), 0, stream>>>(Qs, Ks, Vt, canon, allflag, Wl, bl,
                                                  Ww, fstats, Opart);
  reduce_ao<<<dim3(4096), dim3(256), 0, stream>>>(Opart, bw, Vsum, AO);
  gemm_kernel<<<dim3(64, 16), dim3(256), 0, stream>>>(
      (const float*)nullptr, AO, Wp, bp, out, nullptr, nullptr, nullptr, 1024, 1024, 1);
}